// Round 1
// 676.903 us; speedup vs baseline: 1.0616x; 1.0616x over previous
//
#include <hip/hip_runtime.h>
#include <stdint.h>

// ProgressiveVQ: 8-stage residual VQ, T=131072 rows, D=256, K=1024 codewords/stage.
// out[0:T*D] = recon ; out[T*D..+8] = per-stage MSE (= mean(residual_i^2)).
//
//   vq_prep   : fp32 CB -> bf16 copy, FULL-DEPTH swizzled (byte ^ (cw&31)<<4,
//               bijective in the 512B row) + ||c||^2 table.
//   vq_search : 4-wave blocks, 64 rows/wave as TWO 32-row m-tiles,
//               mfma_f32_32x32x16_bf16. NEW this round:
//                 * 4-buffer LDS ring (was 3) -> ONE barrier per chunk (was 2):
//                   loads issued at iter ch target buf[(ch+2)&3]; its last
//                   reader (chunk ch-2) finished before barrier(ch-1), which
//                   every issuing wave has passed. The old end-of-chunk
//                   barrier (buffer-reuse guard for the 3-ring) is dropped, so
//                   the pack/max tail overlaps neighbors' next-chunk work.
//                 * double-buffered per-stage cnorm table (the dropped tail
//                   barrier also guarded it against next-stage overwrite).
//                 * bottom-issue prefetch + tightened counted waits vmcnt(4)
//                   (same 2-chunk depth), s_setprio(1) around the MFMA cluster
//                   (T5), af-update reordered BEFORE next-stage staging so its
//                   load-waits don't drain the cross-stage prefetch.
//               bf16-carried residual (argmin near-ties only; validated
//               earlier, absmax <=4.5e-3). ||r||^2 recursion gives MSE free.
//   vq_recon  : recon = sum of 8 chosen bf16 codewords (error ~1.6e-5).

#define T_ROWS   131072
#define DIM      256
#define NSTAGE   8
#define NCB      1024
#define WROWS    64             // rows per wave (2 m-tiles of 32)
#define BLK_ROWS 256            // rows per block (4 waves)
#define NTHREADS 256
#define CHUNK_CW 32             // codewords per chunk (16 KiB)
#define NCHUNK   (NCB / CHUNK_CW)          // 32 chunks/stage
#define CHUNK_BYTES (CHUNK_CW * 512)       // 16384

// d_ws layout
#define WS_CB_BYTES    (NSTAGE * NCB * 512)            // bf16 codebooks, swizzled, 4 MiB
#define WS_CNORM_OFF   WS_CB_BYTES
#define WS_CNORM_BYTES (NSTAGE * NCB * 4)
#define WS_MSE_OFF     (WS_CNORM_OFF + WS_CNORM_BYTES)
#define WS_IDX_OFF     (WS_MSE_OFF + 64)               // u16[NSTAGE][T_ROWS], 2 MiB

typedef __attribute__((ext_vector_type(8)))  short  s16x8;
typedef __attribute__((ext_vector_type(8)))  __bf16 bf16x8;
typedef __attribute__((ext_vector_type(4)))  float  f32x4;
typedef __attribute__((ext_vector_type(16))) float  f32x16;

__device__ __forceinline__ unsigned short f2bf(float f) {
  union { float f; unsigned u; } v; v.f = f;
  unsigned r = v.u + 0x7FFFu + ((v.u >> 16) & 1u);   // RNE
  return (unsigned short)(r >> 16);
}

// ---------------------------------------------------------------------------
// Preprocess: fp32 codebooks -> bf16 swizzled copy + ||c||^2.
// ---------------------------------------------------------------------------
__global__ void vq_prep(const float* __restrict__ CB, char* __restrict__ wscb,
                        float* __restrict__ cnorm) {
  const int tid = threadIdx.x;
  const int cwl = tid >> 5;            // 0..7 codeword within block
  const int j   = tid & 31;            // 16B sub-block (covers d = 8j..8j+7)
  const int cw  = blockIdx.x * 8 + cwl;   // 0..8191 = stage*1024 + c
  const int c   = cw & (NCB - 1);
  const float* src = CB + (size_t)cw * DIM + 8 * j;
  f32x4 a = *(const f32x4*)(src);
  f32x4 b = *(const f32x4*)(src + 4);
  s16x8 h;
#pragma unroll
  for (int e = 0; e < 4; ++e) { h[e] = (short)f2bf(a[e]); h[4 + e] = (short)f2bf(b[e]); }
  float sq = a[0]*a[0] + a[1]*a[1] + a[2]*a[2] + a[3]*a[3]
           + b[0]*b[0] + b[1]*b[1] + b[2]*b[2] + b[3]*b[3];
#pragma unroll
  for (int m = 1; m <= 16; m <<= 1) sq += __shfl_xor(sq, m);   // 32-thread group
  // full-depth swizzle: XOR bits 4..8 with (c&31) -> bijective within 512B row
  *(s16x8*)(wscb + (size_t)cw * 512 + ((16 * j) ^ ((c & 31) << 4))) = h;
  if (j == 0) cnorm[cw] = sq;
}

// ---------------------------------------------------------------------------
// Search kernel. 4 waves/block; wave owns 64 rows as TWO 32-row m-tiles.
// 32x32x16 MFMA layouts: A/B: lane l -> k = 8*(l>>5)+e; A row / B col = l&31.
// C/D: col = l&31, row = (reg&3) + 8*(reg>>2) + 4*(l>>5).
// acc init = -||c||^2/2 so argmin dist == argmax acc; codeword index packed
// into low 10 mantissa bits -> fmax-only running argmax.
// ---------------------------------------------------------------------------
__global__ __launch_bounds__(NTHREADS, 2)
void vq_search(const float* __restrict__ X,
               const char* __restrict__ wscb, const float* __restrict__ cnorm,
               unsigned short* __restrict__ IDX, float* __restrict__ wsmse) {
  __shared__ __align__(16) char  lds_cb[4][CHUNK_BYTES];  // 4 x 16 KiB ring
  __shared__ __align__(16) float lds_cn[2][NCB];          // 2 x 4 KiB stage cnorm
  __shared__ int   lds_idx[BLK_ROWS];
  __shared__ float lds_n[BLK_ROWS];

  const int tid  = threadIdx.x;
  const int wave = tid >> 6;
  const int lane = tid & 63;
  const int c32  = lane & 31;          // A row / B,D col within 32-tile
  const int hi   = lane >> 5;          // k-half (A,B) / row-offset (D)

  const int rowbase = blockIdx.x * BLK_ROWS + wave * WROWS;

  // ---- initial approximate residual = bf16(x), A-fragment layout ----
  // tile t: lane holds row rowbase + t*32 + c32; step s covers dims
  // d = 16*s + 8*hi + e, e=0..7
  bf16x8 af[2][16];
  float  sq[2];
#pragma unroll
  for (int t = 0; t < 2; ++t) {
    const float* px = X + (size_t)(rowbase + t * 32 + c32) * DIM + 8 * hi;
    float s2 = 0.f;
#pragma unroll
    for (int s = 0; s < 16; ++s) {
      f32x4 a = *(const f32x4*)(px + 16 * s);
      f32x4 b = *(const f32x4*)(px + 16 * s + 4);
      bf16x8 tt;
#pragma unroll
      for (int e = 0; e < 4; ++e) {
        tt[e] = (__bf16)a[e]; tt[4 + e] = (__bf16)b[e];
        s2 += a[e] * a[e] + b[e] * b[e];
      }
      af[t][s] = tt;
    }
    sq[t] = s2;
  }
  // n0 = ||x||^2 per row: lane's partial covers its k-half; pair with lane^32.
#pragma unroll
  for (int t = 0; t < 2; ++t) {
    float v = sq[t] + __shfl_xor(sq[t], 32);
    if (lane < 32) lds_n[wave * WROWS + t * 32 + c32] = v;
  }

  // ---- prologue: stage-0 cnorm table (bank 0) + chunks 0,1 -> bufs 0,1 ----
  __builtin_amdgcn_global_load_lds(
      (const __attribute__((address_space(1))) char*)((const char*)cnorm + wave * 1024 + lane * 16),
      (__attribute__((address_space(3))) char*)((char*)&lds_cn[0][0] + wave * 1024),
      16, 0, 0);
#pragma unroll
  for (int ch = 0; ch < 2; ++ch)
#pragma unroll
    for (int i = 0; i < 4; ++i) {
      const int seg = (wave * 4 + i) * 1024;
      __builtin_amdgcn_global_load_lds(
          (const __attribute__((address_space(1))) char*)(wscb + (size_t)ch * CHUNK_BYTES + seg + lane * 16),
          (__attribute__((address_space(3))) char*)(&lds_cb[ch][0] + seg),
          16, 0, 0);
    }

  const int swz = c32 << 4;

#pragma unroll 1
  for (int st = 0; st < NSTAGE; ++st) {
    float mv0[16], mv1[16];
#pragma unroll
    for (int r = 0; r < 16; ++r) { mv0[r] = -3.402823466e38f; mv1[r] = -3.402823466e38f; }

    const char* stage_cb = wscb + (size_t)st * NCB * 512;

#pragma unroll 1
    for (int ch = 0; ch < NCHUNK; ++ch) {
      const int cur = ch & 3;

      // top-of-chunk wait: chunk ch's 4 loads were issued at the bottom of
      // iteration ch-2 (or the stage prologue); only chunk ch+1's 4 loads
      // (bottom of ch-1) may stay in flight.
      if (ch < NCHUNK - 1) {
        asm volatile("s_waitcnt vmcnt(4)" ::: "memory");
      } else {
        asm volatile("s_waitcnt vmcnt(0)" ::: "memory");
      }
      __builtin_amdgcn_sched_barrier(0);
      __builtin_amdgcn_s_barrier();          // single barrier/chunk: ch staged
      __builtin_amdgcn_sched_barrier(0);

      const float cn = lds_cn[st & 1][ch * CHUNK_CW + c32];
      const float ci = -0.5f * cn;   // argmin ||r-c||^2 == argmax (r.c - cn/2)
      f32x16 acc0, acc1;
#pragma unroll
      for (int r = 0; r < 16; ++r) { acc0[r] = ci; acc1[r] = ci; }

      const char* buf = &lds_cb[cur][0];
      __builtin_amdgcn_s_setprio(1);
#pragma unroll
      for (int s = 0; s < 16; ++s) {
        bf16x8 b = *(const bf16x8*)(buf + c32 * 512 + ((s * 32 + hi * 16) ^ swz));
        acc0 = __builtin_amdgcn_mfma_f32_32x32x16_bf16(af[0][s], b, acc0, 0, 0, 0);
        acc1 = __builtin_amdgcn_mfma_f32_32x32x16_bf16(af[1][s], b, acc1, 0, 0, 0);
      }
      __builtin_amdgcn_s_setprio(0);

      // bottom-issue prefetch for chunk ch+2 into buf[(ch+2)&3].
      // Safety: past barrier(ch), every wave finished compute(ch-1), hence
      // all reads of buf[(ch+2)&3] (= chunk ch-2) completed. LDS-write vs
      // ds_read ordering keeps these after the s-loop's reads of buf[cur].
      if (ch + 2 < NCHUNK) {
        const char* src = stage_cb + (size_t)(ch + 2) * CHUNK_BYTES;
        char* dst = &lds_cb[(ch + 2) & 3][0];
#pragma unroll
        for (int i = 0; i < 4; ++i) {
          const int seg = (wave * 4 + i) * 1024;
          __builtin_amdgcn_global_load_lds(
              (const __attribute__((address_space(1))) char*)(src + seg + lane * 16),
              (__attribute__((address_space(3))) char*)(dst + seg),
              16, 0, 0);
        }
      }

      const unsigned col = (unsigned)(ch * CHUNK_CW + c32);
#pragma unroll
      for (int r = 0; r < 16; ++r) {
        union { float f; unsigned u; } p0, p1;
        p0.f = acc0[r]; p0.u = (p0.u & 0xFFFFFC00u) | col;
        p1.f = acc1[r]; p1.u = (p1.u & 0xFFFFFC00u) | col;
        mv0[r] = fmaxf(mv0[r], p0.f);
        mv1[r] = fmaxf(mv1[r], p1.f);
      }
      // no end-of-chunk barrier: 4-deep ring makes the reuse distance 2
      // barriers, and the top-of-chunk barrier orders everything else.
    }

    // ---- cross-lane argmax + ||r||^2 recursion ----
    // (t,r): row = t*32 + (r&3) + 8*(r>>2) + 4*hi ; reduce over the 32 cols
    float msum = 0.f;
#pragma unroll
    for (int t = 0; t < 2; ++t)
#pragma unroll
      for (int r = 0; r < 16; ++r) {
        float v = (t == 0) ? mv0[r] : mv1[r];
#pragma unroll
        for (int m = 1; m <= 16; m <<= 1) v = fmaxf(v, __shfl_xor(v, m));
        union { float f; unsigned u; } w; w.f = v;
        const float vtrue = __builtin_bit_cast(float, w.u & 0xFFFFFC00u);
        const int   row   = t * 32 + (r & 3) + 8 * (r >> 2) + 4 * hi;
        const int   wrow  = wave * WROWS + row;
        const float n_new = lds_n[wrow] - 2.0f * vtrue;   // min-dist identity
        msum += n_new;
        if (c32 == 0) {
          lds_n[wrow]   = n_new;
          const int ix = (int)(w.u & 1023u);
          lds_idx[wrow] = ix;
          IDX[st * T_ROWS + rowbase + row] = (unsigned short)ix;
        }
      }
    // msum uniform within each 32-lane half; halves cover disjoint rows
    msum += __shfl_xor(msum, 32);
    if (lane == 0) atomicAdd(wsmse + st, msum);

    if (st != NSTAGE - 1) {
      // ---- approximate af update from bf16 wscb (ranking only) FIRST, so
      //      the compiler's waits on these loads don't drain the next-stage
      //      staging issued below ----
      // lane needs codeword of row t*32 + c32, its k-half dims
#pragma unroll
      for (int t = 0; t < 2; ++t) {
        const int idx = lds_idx[wave * WROWS + t * 32 + c32];
        const char* q = stage_cb + (size_t)idx * 512;
        const int swzu = (idx & 31) << 4;
#pragma unroll
        for (int s = 0; s < 16; ++s) {
          bf16x8 qb = *(const bf16x8*)(q + ((s * 32 + hi * 16) ^ swzu));
          bf16x8 tt = af[t][s];
#pragma unroll
          for (int e = 0; e < 8; ++e)
            tt[e] = (__bf16)((float)tt[e] - (float)qb[e]);
          af[t][s] = tt;
        }
      }
      __builtin_amdgcn_sched_barrier(0);

      // ---- issue next stage's cnorm (other bank) + chunks 0,1 -> bufs 0,1.
      //      Safety vs lagging waves: we passed barrier(31), so every wave
      //      finished compute(30); bufs 0,1,2 and cn bank (st+1)&1 are free
      //      (only buf3 = chunk 31 is still being read). ----
      const char* ncb = stage_cb + (size_t)NCB * 512;
      const char* ncn = (const char*)cnorm + (size_t)(st + 1) * NCB * 4;
      __builtin_amdgcn_global_load_lds(
          (const __attribute__((address_space(1))) char*)(ncn + wave * 1024 + lane * 16),
          (__attribute__((address_space(3))) char*)((char*)&lds_cn[(st + 1) & 1][0] + wave * 1024),
          16, 0, 0);
#pragma unroll
      for (int ch = 0; ch < 2; ++ch)
#pragma unroll
        for (int i = 0; i < 4; ++i) {
          const int seg = (wave * 4 + i) * 1024;
          __builtin_amdgcn_global_load_lds(
              (const __attribute__((address_space(1))) char*)(ncb + (size_t)ch * CHUNK_BYTES + seg + lane * 16),
              (__attribute__((address_space(3))) char*)(&lds_cb[ch][0] + seg),
              16, 0, 0);
        }
      // note: barrier before next stage's first read is the ch=0 iteration's
      // wait+barrier; lds_idx/lds_n slots are per-wave (same-wave DS ordering)
    }
  }
}

// ---------------------------------------------------------------------------
// Recon kernel: OUT[row] = sum of the 8 chosen bf16 codewords.
// Reads only wscb (4 MB, L2-resident) + IDX (2 MB). 8 threads/row.
// ---------------------------------------------------------------------------
__global__ __launch_bounds__(256)
void vq_recon(const char* __restrict__ wscb, const unsigned short* __restrict__ IDX,
              float* __restrict__ OUT) {
  const int tid = threadIdx.x;
  const int row = blockIdx.x * (256 / 8) + (tid >> 3);
  const int g   = tid & 7;             // dims g*32 .. g*32+31

  int idxs[NSTAGE];
#pragma unroll
  for (int st = 0; st < NSTAGE; ++st) idxs[st] = IDX[st * T_ROWS + row];

  float a[32];
#pragma unroll
  for (int d = 0; d < 32; ++d) a[d] = 0.f;

#pragma unroll
  for (int st = 0; st < NSTAGE; ++st) {
    const char* q = wscb + ((size_t)st * NCB + idxs[st]) * 512;
    const int swzu = (idxs[st] & 31) << 4;
#pragma unroll
    for (int k = 0; k < 4; ++k) {
      bf16x8 qb = *(const bf16x8*)(q + ((g * 64 + 16 * k) ^ swzu));
#pragma unroll
      for (int e = 0; e < 8; ++e) a[k * 8 + e] += (float)qb[e];
    }
  }

  float* po = OUT + (size_t)row * DIM + g * 32;
#pragma unroll
  for (int m = 0; m < 8; ++m) {
    f32x4 o = {a[4 * m], a[4 * m + 1], a[4 * m + 2], a[4 * m + 3]};
    *(f32x4*)(po + 4 * m) = o;
  }
}

__global__ void vq_fin(const float* __restrict__ wsmse, float* __restrict__ OUT) {
  const int i = threadIdx.x;
  if (i < NSTAGE) {
    OUT[(size_t)T_ROWS * DIM + i] = wsmse[i] * (1.0f / ((float)T_ROWS * (float)DIM));
  }
}

extern "C" void kernel_launch(void* const* d_in, const int* in_sizes, int n_in,
                              void* d_out, int out_size, void* d_ws, size_t ws_size,
                              hipStream_t stream) {
  (void)in_sizes; (void)n_in; (void)out_size; (void)ws_size;
  const float* X  = (const float*)d_in[0];
  const float* CB = (const float*)d_in[1];
  float* OUT = (float*)d_out;
  char*  wscb  = (char*)d_ws;
  float* cnorm = (float*)((char*)d_ws + WS_CNORM_OFF);
  float* wsmse = (float*)((char*)d_ws + WS_MSE_OFF);
  unsigned short* IDX = (unsigned short*)((char*)d_ws + WS_IDX_OFF);

  hipMemsetAsync(wsmse, 0, NSTAGE * sizeof(float), stream);
  hipLaunchKernelGGL(vq_prep, dim3((NSTAGE * NCB) / 8), dim3(256), 0, stream,
                     CB, wscb, cnorm);
  hipLaunchKernelGGL(vq_search, dim3(T_ROWS / BLK_ROWS), dim3(NTHREADS), 0, stream,
                     X, wscb, cnorm, IDX, wsmse);
  hipLaunchKernelGGL(vq_recon, dim3(T_ROWS / (256 / 8)), dim3(256), 0, stream,
                     wscb, IDX, OUT);
  hipLaunchKernelGGL(vq_fin, dim3(1), dim3(64), 0, stream, wsmse, OUT);
}